// Round 5
// baseline (6189.062 us; speedup 1.0000x reference)
//
#include <hip/hip_runtime.h>

// ---------------- problem constants ----------------
#define BB 64      // batch
#define SS 512     // seq len
#define II 1024    // input dim
#define HH 1024    // hidden
#define G4 4096    // 4*H fused gates
#define NWG_REC 64 // workgroups in recurrent kernel (proven co-resident count)

typedef unsigned short u16;
typedef unsigned int u32;
typedef unsigned long long u64;

typedef short s16x8 __attribute__((ext_vector_type(8)));   // 8 bf16 MFMA A/B frag
typedef float f32x4 __attribute__((ext_vector_type(4)));   // MFMA C/D frag
typedef u32   u32x4 __attribute__((ext_vector_type(4)));

typedef __attribute__((address_space(1))) const u32 as1_uint_t;
typedef __attribute__((address_space(3))) u32 as3_uint_t;

__device__ __forceinline__ u16 f2bf(float f) {   // RNE float->bf16
    u32 x = __float_as_uint(f);
    x += 0x7fffu + ((x >> 16) & 1u);
    return (u16)(x >> 16);
}
__device__ __forceinline__ float bf2f(u16 v) {
    return __uint_as_float(((u32)v) << 16);
}
__device__ __forceinline__ f32x4 mfma16(s16x8 a, s16x8 b, f32x4 c) {
    return __builtin_amdgcn_mfma_f32_16x16x32_bf16(a, b, c, 0, 0, 0);
}
__device__ __forceinline__ float fsigm(float x) { return 1.f / (1.f + __expf(-x)); }
__device__ __forceinline__ float ftanh(float x) {
    float e = __expf(2.f * x);
    return (e - 1.f) / (e + 1.f);
}

// LLC-coherent 16B load (bypass L1/L2, pipelined)
#define HL(dst, ptr, OFF) \
    asm volatile("global_load_dwordx4 %0, %1, off offset:%2 sc0 sc1" \
                 : "=v"(dst) : "v"(ptr), "n"(OFF))
#define XL32(dst, ptr) \
    asm volatile("global_load_dword %0, %1, off" : "=v"(dst) : "v"(ptr))
// wait until ≤N vmem outstanding; pins the 8 dwordx4 of one chunk as deps
#define WAITAV8(N, A) \
    asm volatile("s_waitcnt vmcnt(%8)" \
                 : "+v"((A)[0]), "+v"((A)[1]), "+v"((A)[2]), "+v"((A)[3]), \
                   "+v"((A)[4]), "+v"((A)[5]), "+v"((A)[6]), "+v"((A)[7]) \
                 : "n"(N))
// issue one chunk (4 kk = 8 dwordx4) of tagged h rows into slot s
#define ISSUE_CHUNK(s, cc) do { \
    HL(av[s][0], hrp, (cc)*512 + 0);   HL(av[s][1], hrp, (cc)*512 + 16);  \
    HL(av[s][2], hrp, (cc)*512 + 128); HL(av[s][3], hrp, (cc)*512 + 144); \
    HL(av[s][4], hrp, (cc)*512 + 256); HL(av[s][5], hrp, (cc)*512 + 272); \
    HL(av[s][6], hrp, (cc)*512 + 384); HL(av[s][7], hrp, (cc)*512 + 400); \
} while (0)

// ---------------- prep: x fp32 -> bf16 ----------------
__global__ __launch_bounds__(256) void k_convert_x(const float* __restrict__ x,
                                                   u16* __restrict__ xb, int n4) {
    int i = blockIdx.x * 256 + threadIdx.x;
    int stride = gridDim.x * 256;
    const float4* xv = (const float4*)x;
    u64* ov = (u64*)xb;
    for (; i < n4; i += stride) {
        float4 v = xv[i];
        u64 o = (u64)f2bf(v.x) | ((u64)f2bf(v.y) << 16) |
                ((u64)f2bf(v.z) << 32) | ((u64)f2bf(v.w) << 48);
        ov[i] = o;
    }
}

// ---------------- prep: A[R][C] fp32 -> At[C][R] bf16 ----------------
__global__ __launch_bounds__(1024) void k_transpose_bf(const float* __restrict__ A,
                                                       u16* __restrict__ At, int R, int C) {
    __shared__ float tile[32][33];
    int cb = blockIdx.x * 32, rb = blockIdx.y * 32;
    int tx = threadIdx.x, ty = threadIdx.y;
    tile[ty][tx] = A[(size_t)(rb + ty) * C + cb + tx];
    __syncthreads();
    At[(size_t)(cb + ty) * R + rb + tx] = f2bf(tile[tx][ty]);
}

// ---------------- prep: zero tagged-h double buffer (512KB) + sync area (4KB) ---------
__global__ __launch_bounds__(256) void k_zero(u64* hb, u64* cnt) {
    int i = blockIdx.x * 256 + threadIdx.x;
    int stride = gridDim.x * 256;
    const int n = 2 * BB * HH * 4 / 8;   // tagged u32 double buffer, bytes/8
    for (; i < n; i += stride) hb[i] = 0ull;
    if (blockIdx.x == 0 && threadIdx.x < 512) cnt[threadIdx.x] = 0ull;
}

// ---------------- phase 1: xW = x@W + b  (bf16 MFMA, out row-permuted [s][b][4H]) -----
template <bool XW32>
__global__ __launch_bounds__(256) void k_gemm_xw(const u16* __restrict__ Abf,
                                                 const u16* __restrict__ Bt,
                                                 const float* __restrict__ bias,
                                                 void* __restrict__ xw) {
    __shared__ u16 As[128 * 32];
    __shared__ u16 Bs[128 * 32];
    int bid = blockIdx.x;
    int wid = (bid & 7) * 1024 + (bid >> 3);   // XCD-chunked swizzle
    int mt = wid & 255, nt = wid >> 8;
    size_t rb = (size_t)mt * 128;
    int cb = nt * 128;
    int tid = threadIdx.x;
    int w = tid >> 6, l = tid & 63;
    int lr = l >> 4, lc = l & 15;
    int wr = (w >> 1) * 64, wc = (w & 1) * 64;
    f32x4 acc[4][4] = {};
    for (int kb = 0; kb < II; kb += 32) {
        __syncthreads();
#pragma unroll
        for (int q = 0; q < 2; ++q) {
            int bo = q * 4096 + w * 1024 + l * 16;
            int row = bo >> 6;
            int off = (bo & 63) >> 1;
            const u16* srcA = Abf + (rb + row) * II + kb + off;
            __builtin_amdgcn_global_load_lds((as1_uint_t*)srcA,
                (as3_uint_t*)((char*)As + q * 4096 + w * 1024), 16, 0, 0);
            const u16* srcB = Bt + (size_t)(cb + row) * II + kb + off;
            __builtin_amdgcn_global_load_lds((as1_uint_t*)srcB,
                (as3_uint_t*)((char*)Bs + q * 4096 + w * 1024), 16, 0, 0);
        }
        __syncthreads();
        s16x8 af[4], bf[4];
#pragma unroll
        for (int m = 0; m < 4; ++m)
            af[m] = *(const s16x8*)(As + (wr + m * 16 + lc) * 32 + lr * 8);
#pragma unroll
        for (int n = 0; n < 4; ++n)
            bf[n] = *(const s16x8*)(Bs + (wc + n * 16 + lc) * 32 + lr * 8);
#pragma unroll
        for (int m = 0; m < 4; ++m)
#pragma unroll
            for (int n = 0; n < 4; ++n)
                acc[m][n] = mfma16(af[m], bf[n], acc[m][n]);
    }
    float bv[4];
#pragma unroll
    for (int n = 0; n < 4; ++n) bv[n] = bias[cb + wc + n * 16 + lc];
#pragma unroll
    for (int m = 0; m < 4; ++m) {
#pragma unroll
        for (int r = 0; r < 4; ++r) {
            size_t g = rb + wr + m * 16 + lr * 4 + r;       // global row b*512+s
            size_t srow = ((g & 511) << 6) | (g >> 9);      // s*64 + b
#pragma unroll
            for (int n = 0; n < 4; ++n) {
                float v = acc[m][n][r] + bv[n];
                size_t idx = srow * G4 + cb + wc + n * 16 + lc;
                if (XW32) ((float*)xw)[idx] = v;
                else      ((u16*)xw)[idx] = f2bf(v);
            }
        }
    }
}

// ---------------- phase 2: persistent recurrent kernel, barrier-free -----------------
// 64 WGs x 4 waves; each wave fully independent after U-staging (no __syncthreads in
// the loop). h exchanged as TAGGED u32 (bf16<<16 | step) in a double buffer: the data
// is the flag. Consumer: canary pre-poll (1 load/lane) then pipelined chunk loads with
// per-chunk sum-verify (mod 2^16) + v_perm repack + MFMA. Producer: fire-and-forget
// tagged stores + canary; no ack wait, no atomics, no fences.
template <bool XW32>
__global__ __launch_bounds__(256, 1) void k_lstm5(const u16* __restrict__ Ut,
                                                  const void* __restrict__ xw,
                                                  u32* hb32, u32* sync,
                                                  float* __restrict__ out) {
    __shared__ u16 Us[8192 * 8];   // chunk ch=((kk*4+g)*4+lr)*16+lc -> 8 bf16
    const int j = blockIdx.x;
    const int tid = threadIdx.x;
    const int w = tid >> 6, l = tid & 63;
    const int lr = l >> 4, lc = l & 15;
    const int rowbase = w * 16;
    const int col = j * 16 + lc;

    // ---- stage U slice into LDS (one-time) ----
    for (int i = 0; i < 32; ++i) {
        int ch = tid + (i << 8);
        int lc2 = ch & 15, lr2 = (ch >> 4) & 3, g2 = (ch >> 6) & 3, kk2 = ch >> 8;
        const u16* src = Ut + (size_t)(g2 * HH + j * 16 + lc2) * II + kk2 * 32 + lr2 * 8;
        *(s16x8*)(Us + (size_t)ch * 8) = *(const s16x8*)src;
    }

    float cc[4] = {0.f, 0.f, 0.f, 0.f};
    const size_t xwlane = (size_t)(rowbase + lr * 4) * G4 + col;

    const char* xwp[16];
#pragma unroll
    for (int g = 0; g < 4; ++g)
#pragma unroll
        for (int r = 0; r < 4; ++r) {
            size_t e = (size_t)BB * G4 + xwlane + (size_t)r * G4 + (size_t)g * HH;
            xwp[g * 4 + r] = (const char*)xw + (XW32 ? e * 4 : e * 2);
        }

    float cur[16];
#pragma unroll
    for (int g = 0; g < 4; ++g)
#pragma unroll
        for (int r = 0; r < 4; ++r) {
            size_t e = xwlane + (size_t)r * G4 + (size_t)g * HH;
            cur[g * 4 + r] = XW32 ? ((const float*)xw)[e] : bf2f(((const u16*)xw)[e]);
        }

    const u32* cpoll = sync + w * 64 + l;     // canary this lane polls
    u32* cpub = sync + w * 64 + j;            // canary this wave publishes (lane 0)
    float burn = 1.0f;
    const float burnc = 1.0000001f;

    __syncthreads();   // Us ready; last barrier — waves are independent from here on

    for (int t = 0; t < SS; ++t) {
        // ---- canary pre-poll: all step-(t-1) producers published (value >= t) ----
        // vmcnt(0) inside also drains our own stores + xw prefetch of last step.
        {
            u32 cv;
            while (true) {
                asm volatile("global_load_dword %0, %1, off sc0 sc1\n\t"
                             "s_waitcnt vmcnt(0)"
                             : "=v"(cv) : "v"(cpoll) : "memory");
                if (__all((int)(cv >= (u32)t))) break;
#pragma unroll
                for (int i = 0; i < 16; ++i)   // keep issue alive (anti-DVFS)
                    asm volatile("v_fmac_f32 %0, %1, %2" : "+v"(burn) : "v"(burnc), "v"(burn));
            }
        }

        u32 nxt[16];
        if (t > 0) {   // xw(t) landed (drained by poll); ordering glue then consume
            asm volatile("" : "+v"(nxt[0]), "+v"(nxt[1]), "+v"(nxt[2]), "+v"(nxt[3]),
                             "+v"(nxt[4]), "+v"(nxt[5]), "+v"(nxt[6]), "+v"(nxt[7]),
                             "+v"(nxt[8]), "+v"(nxt[9]), "+v"(nxt[10]), "+v"(nxt[11]),
                             "+v"(nxt[12]), "+v"(nxt[13]), "+v"(nxt[14]), "+v"(nxt[15]));
#pragma unroll
            for (int q = 0; q < 16; ++q)
                cur[q] = XW32 ? __uint_as_float(nxt[q]) : __uint_as_float(nxt[q] << 16);
        }

        f32x4 acc[4][4];
#pragma unroll
        for (int g = 0; g < 4; ++g) {
#pragma unroll
            for (int r = 0; r < 4; ++r) acc[g][0][r] = cur[g * 4 + r];
            acc[g][1] = f32x4{0.f, 0.f, 0.f, 0.f};
            acc[g][2] = f32x4{0.f, 0.f, 0.f, 0.f};
            acc[g][3] = f32x4{0.f, 0.f, 0.f, 0.f};
        }

        // ---- pipelined tagged-h consumption: 8 chunks, depth-4 ----
        const u32* hrp = hb32 + ((size_t)(t & 1) << 16) +
                         (size_t)(rowbase + lc) * 1024 + lr * 8;
        u32x4 av[4][8];
        ISSUE_CHUNK(0, 0); ISSUE_CHUNK(1, 1); ISSUE_CHUNK(2, 2); ISSUE_CHUNK(3, 3);

        constexpr int WT[8] = {24, 24, 24, 24, 24, 16, 8, 0};
        const u32 expsum = 32u * (u32)t;
#pragma unroll
        for (int c = 0; c < 8; ++c) {
            const int s = c & 3;
            WAITAV8(WT[c], av[s]);
            // verify: sum of 32 tagged words mod 2^16 == 32*t (stale tags differ)
            u32x4 t0 = av[s][0] + av[s][1], t1 = av[s][2] + av[s][3];
            u32x4 t2 = av[s][4] + av[s][5], t3 = av[s][6] + av[s][7];
            u32x4 t4 = t0 + t1 + t2 + t3;
            u32 sum = t4.x + t4.y + t4.z + t4.w;
            while (__any((int)(((sum - expsum) & 0xFFFFu) != 0u))) {
                ISSUE_CHUNK(s, c);
                WAITAV8(0, av[s]);
                u32x4 r0 = av[s][0] + av[s][1], r1 = av[s][2] + av[s][3];
                u32x4 r2 = av[s][4] + av[s][5], r3 = av[s][6] + av[s][7];
                u32x4 r4 = r0 + r1 + r2 + r3;
                sum = r4.x + r4.y + r4.z + r4.w;
            }
            // repack hi16s -> bf16 frags
            s16x8 pk[4];
#pragma unroll
            for (int kq = 0; kq < 4; ++kq) {
                u32x4 xlo = av[s][2 * kq], xhi = av[s][2 * kq + 1];
                union { u32 u[4]; s16x8 v; } p;
                p.u[0] = __builtin_amdgcn_perm(xlo.y, xlo.x, 0x07060302);
                p.u[1] = __builtin_amdgcn_perm(xlo.w, xlo.z, 0x07060302);
                p.u[2] = __builtin_amdgcn_perm(xhi.y, xhi.x, 0x07060302);
                p.u[3] = __builtin_amdgcn_perm(xhi.w, xhi.z, 0x07060302);
                pk[kq] = p.v;
            }
            if (c < 4) ISSUE_CHUNK(s, c + 4);   // refill freed slot
#pragma unroll
            for (int kq = 0; kq < 4; ++kq) {
                const int kk = c * 4 + kq;
#pragma unroll
                for (int g = 0; g < 4; ++g) {
                    const s16x8 bv = *(const s16x8*)(Us +
                        (size_t)(((kk * 4 + g) * 4 + lr) * 16 + lc) * 8);
                    acc[g][kq] = mfma16(pk[kq], bv, acc[g][kq]);
                }
            }
        }

        // ---- xw(t+1) prefetch (drained for free by next step's poll) ----
        if (t < SS - 1) {
#pragma unroll
            for (int q = 0; q < 16; ++q) {
                if (XW32) { XL32(nxt[q], xwp[q]); }
                else {
                    asm volatile("global_load_ushort %0, %1, off"
                                 : "=v"(nxt[q]) : "v"(xwp[q]));
                }
            }
            if (t < SS - 2) {
#pragma unroll
                for (int q = 0; q < 16; ++q)
                    xwp[q] += (size_t)BB * G4 * (XW32 ? 4 : 2);
            }
        }

        // ---- activations + cell update ----
        float hval[4];
#pragma unroll
        for (int r = 0; r < 4; ++r) {
            float gi = (acc[0][0][r] + acc[0][1][r]) + (acc[0][2][r] + acc[0][3][r]);
            float gf = (acc[1][0][r] + acc[1][1][r]) + (acc[1][2][r] + acc[1][3][r]);
            float gg = (acc[2][0][r] + acc[2][1][r]) + (acc[2][2][r] + acc[2][3][r]);
            float go = (acc[3][0][r] + acc[3][1][r]) + (acc[3][2][r] + acc[3][3][r]);
            float i_ = fsigm(gi);
            float f_ = fsigm(gf);
            float g_ = ftanh(gg);
            float o_ = fsigm(go);
            cc[r] = f_ * cc[r] + i_ * g_;
            hval[r] = o_ * ftanh(cc[r]);
        }

        if (t < SS - 1) {
            // ---- publish: tagged h stores then canary, all fire-and-forget ----
            u32* hwp = hb32 + ((size_t)((t + 1) & 1) << 16);
            const u32 tagv = (u32)(t + 1);
#pragma unroll
            for (int r = 0; r < 4; ++r) {
                int row = rowbase + lr * 4 + r;
                u32 val = ((u32)f2bf(hval[r]) << 16) | tagv;
                u32* ad = hwp + (size_t)row * 1024 + col;
                asm volatile("global_store_dword %0, %1, off sc0 sc1"
                             :: "v"(ad), "v"(val) : "memory");
            }
            if (l == 0)
                asm volatile("global_store_dword %0, %1, off sc0 sc1"
                             :: "v"(cpub), "v"(tagv) : "memory");
            // out stores after publish (overlap next poll)
#pragma unroll
            for (int r = 0; r < 4; ++r) {
                int row = rowbase + lr * 4 + r;
                out[(size_t)row * (SS * HH) + (size_t)t * HH + col] = hval[r];
            }
        } else {
#pragma unroll
            for (int r = 0; r < 4; ++r) {
                int row = rowbase + lr * 4 + r;
                out[(size_t)row * (SS * HH) + (size_t)t * HH + col] = hval[r];
                out[(size_t)(BB * SS * HH) + (size_t)row * HH + col] = hval[r];
                out[(size_t)(BB * SS * HH + BB * HH) + (size_t)row * HH + col] = cc[r];
            }
        }
    }
    asm volatile("" :: "v"(burn));
}

// ---------------- host launch ----------------
extern "C" void kernel_launch(void* const* d_in, const int* in_sizes, int n_in,
                              void* d_out, int out_size, void* d_ws, size_t ws_size,
                              hipStream_t stream) {
    const float* x = (const float*)d_in[0];
    const float* W = (const float*)d_in[1];
    const float* U = (const float*)d_in[2];
    const float* b = (const float*)d_in[3];
    float* out = (float*)d_out;

    size_t xb_b  = (size_t)BB * SS * II * 2;   // 64 MiB
    size_t wt_b  = (size_t)G4 * II * 2;        // 8 MiB each
    size_t hb_b  = (size_t)2 * BB * HH * 4;    // 512 KiB tagged double buffer
    size_t xw32_b = (size_t)BB * SS * G4 * 4;  // 512 MiB
    size_t xw16_b = xw32_b / 2;
    size_t base = xb_b + 2 * wt_b;

    int mode = (base + xw32_b + hb_b + 4096 <= ws_size) ? 0 : 1;

    char* p = (char*)d_ws;
    u16* xb = (u16*)p;
    u16* Wt = (u16*)(p + xb_b);
    u16* Ut = (u16*)(p + xb_b + wt_b);
    char* q = p + base;
    void* xw = (void*)q;
    q += (mode == 0) ? xw32_b : xw16_b;
    u32* hb32 = (u32*)q; q += hb_b;
    u32* sync = (u32*)q;   // 4KB: 256 canaries + padding

    k_convert_x<<<2048, 256, 0, stream>>>(x, xb, BB * SS * II / 4);
    k_transpose_bf<<<dim3(G4 / 32, II / 32), dim3(32, 32), 0, stream>>>(W, Wt, II, G4);
    k_transpose_bf<<<dim3(G4 / 32, II / 32), dim3(32, 32), 0, stream>>>(U, Ut, II, G4);
    k_zero<<<64, 256, 0, stream>>>((u64*)hb32, (u64*)sync);

    if (mode == 0) {
        k_gemm_xw<true><<<8192, 256, 0, stream>>>(xb, Wt, b, xw);
        k_lstm5<true><<<NWG_REC, 256, 0, stream>>>(Ut, xw, hb32, sync, out);
    } else {
        k_gemm_xw<false><<<8192, 256, 0, stream>>>(xb, Wt, b, xw);
        k_lstm5<false><<<NWG_REC, 256, 0, stream>>>(Ut, xw, hb32, sync, out);
    }
}

// Round 9
// 5110.932 us; speedup vs baseline: 1.2109x; 1.2109x over previous
//
#include <hip/hip_runtime.h>

// ---------------- problem constants ----------------
#define BB 64      // batch
#define SS 512     // seq len
#define II 1024    // input dim
#define HH 1024    // hidden
#define G4 4096    // 4*H fused gates
#define NWG_REC 64 // recurrence workgroups
#define NWG_TOT 256

typedef unsigned short u16;
typedef unsigned int u32;
typedef unsigned long long u64;

typedef short s16x8 __attribute__((ext_vector_type(8)));   // 8 bf16 MFMA A/B frag
typedef float f32x4 __attribute__((ext_vector_type(4)));   // MFMA C/D frag

typedef __attribute__((address_space(1))) const u32 as1_uint_t;
typedef __attribute__((address_space(3))) u32 as3_uint_t;

#define SBAR() __builtin_amdgcn_sched_barrier(0)

__device__ __forceinline__ u16 f2bf(float f) {   // RNE float->bf16
    u32 x = __float_as_uint(f);
    x += 0x7fffu + ((x >> 16) & 1u);
    return (u16)(x >> 16);
}
__device__ __forceinline__ float bf2f(u16 v) {
    return __uint_as_float(((u32)v) << 16);
}
__device__ __forceinline__ f32x4 mfma16(s16x8 a, s16x8 b, f32x4 c) {
    return __builtin_amdgcn_mfma_f32_16x16x32_bf16(a, b, c, 0, 0, 0);
}
__device__ __forceinline__ float fsigm(float x) { return 1.f / (1.f + __expf(-x)); }
__device__ __forceinline__ float ftanh(float x) {
    float e = __expf(2.f * x);
    return (e - 1.f) / (e + 1.f);
}

// LLC-coherent loads (bypass L1/L2, pipelined) — R2-R5-proven
#define HL(dst, ptr, OFF) \
    asm volatile("global_load_dwordx4 %0, %1, off offset:%2 sc0 sc1" \
                 : "=v"(dst) : "v"(ptr), "n"(OFF))
// plain loads for xw (written by a PRIOR kernel — caches valid) — R4-proven
#define XL32(dst, ptr) \
    asm volatile("global_load_dword %0, %1, off" : "=v"(dst) : "v"(ptr))
#define XL16(dst, ptr) \
    asm volatile("global_load_ushort %0, %1, off" : "=v"(dst) : "v"(ptr))
#define POLLC(dst, ptr) \
    asm volatile("global_load_dword %0, %1, off sc0 sc1\n\ts_waitcnt vmcnt(0)" \
                 : "=v"(dst) : "v"(ptr) : "memory")
// counted wait pinning the 8 frag registers about to be consumed
#define WAITAV8(N, A) \
    asm volatile("s_waitcnt vmcnt(%8)" \
                 : "+v"((A)[0]), "+v"((A)[1]), "+v"((A)[2]), "+v"((A)[3]), \
                   "+v"((A)[4]), "+v"((A)[5]), "+v"((A)[6]), "+v"((A)[7]) \
                 : "n"(N))
// full drain with the 16 xw-prefetch registers pinned
#define DRAIN16(A) \
    asm volatile("s_waitcnt vmcnt(0)" \
                 : "+v"((A)[0]), "+v"((A)[1]), "+v"((A)[2]), "+v"((A)[3]), \
                   "+v"((A)[4]), "+v"((A)[5]), "+v"((A)[6]), "+v"((A)[7]), \
                   "+v"((A)[8]), "+v"((A)[9]), "+v"((A)[10]), "+v"((A)[11]), \
                   "+v"((A)[12]), "+v"((A)[13]), "+v"((A)[14]), "+v"((A)[15]) \
                 :: "memory")

// ---------------- prep: x fp32 -> bf16 ----------------
__global__ __launch_bounds__(256) void k_convert_x(const float* __restrict__ x,
                                                   u16* __restrict__ xb, int n4) {
    int i = blockIdx.x * 256 + threadIdx.x;
    int stride = gridDim.x * 256;
    const float4* xv = (const float4*)x;
    u64* ov = (u64*)xb;
    for (; i < n4; i += stride) {
        float4 v = xv[i];
        u64 o = (u64)f2bf(v.x) | ((u64)f2bf(v.y) << 16) |
                ((u64)f2bf(v.z) << 32) | ((u64)f2bf(v.w) << 48);
        ov[i] = o;
    }
}

// ---------------- prep: A[R][C] fp32 -> At[C][R] bf16 ----------------
__global__ __launch_bounds__(1024) void k_transpose_bf(const float* __restrict__ A,
                                                       u16* __restrict__ At, int R, int C) {
    __shared__ float tile[32][33];
    int cb = blockIdx.x * 32, rb = blockIdx.y * 32;
    int tx = threadIdx.x, ty = threadIdx.y;
    tile[ty][tx] = A[(size_t)(rb + ty) * C + cb + tx];
    __syncthreads();
    At[(size_t)(cb + ty) * R + rb + tx] = f2bf(tile[tx][ty]);
}

// ---------------- prep: zero h double buffer (256KB) + sync area (4KB) ----------------
__global__ __launch_bounds__(256) void k_zero(u64* hb, u64* cnt) {
    int i = blockIdx.x * 256 + threadIdx.x;
    int stride = gridDim.x * 256;
    const int n = 2 * BB * HH * 2 / 8;
    for (; i < n; i += stride) hb[i] = 0ull;
    if (blockIdx.x == 0 && threadIdx.x < 512) cnt[threadIdx.x] = 0ull;
}

// ---------------- phase 1: xW = x@W + b  (bf16 MFMA, out row-permuted [s][b][4H]) -----
// R1-R5-proven verbatim.
template <bool XW32>
__global__ __launch_bounds__(256) void k_gemm_xw(const u16* __restrict__ Abf,
                                                 const u16* __restrict__ Bt,
                                                 const float* __restrict__ bias,
                                                 void* __restrict__ xw) {
    __shared__ u16 As[128 * 32];
    __shared__ u16 Bs[128 * 32];
    int bid = blockIdx.x;
    int wid = (bid & 7) * 1024 + (bid >> 3);   // XCD-chunked swizzle
    int mt = wid & 255, nt = wid >> 8;
    size_t rb = (size_t)mt * 128;
    int cb = nt * 128;
    int tid = threadIdx.x;
    int w = tid >> 6, l = tid & 63;
    int lr = l >> 4, lc = l & 15;
    int wr = (w >> 1) * 64, wc = (w & 1) * 64;
    f32x4 acc[4][4] = {};
    for (int kb = 0; kb < II; kb += 32) {
        __syncthreads();
#pragma unroll
        for (int q = 0; q < 2; ++q) {
            int bo = q * 4096 + w * 1024 + l * 16;
            int row = bo >> 6;
            int off = (bo & 63) >> 1;
            const u16* srcA = Abf + (rb + row) * II + kb + off;
            __builtin_amdgcn_global_load_lds((as1_uint_t*)srcA,
                (as3_uint_t*)((char*)As + q * 4096 + w * 1024), 16, 0, 0);
            const u16* srcB = Bt + (size_t)(cb + row) * II + kb + off;
            __builtin_amdgcn_global_load_lds((as1_uint_t*)srcB,
                (as3_uint_t*)((char*)Bs + q * 4096 + w * 1024), 16, 0, 0);
        }
        __syncthreads();
        s16x8 af[4], bf[4];
#pragma unroll
        for (int m = 0; m < 4; ++m)
            af[m] = *(const s16x8*)(As + (wr + m * 16 + lc) * 32 + lr * 8);
#pragma unroll
        for (int n = 0; n < 4; ++n)
            bf[n] = *(const s16x8*)(Bs + (wc + n * 16 + lc) * 32 + lr * 8);
#pragma unroll
        for (int m = 0; m < 4; ++m)
#pragma unroll
            for (int n = 0; n < 4; ++n)
                acc[m][n] = mfma16(af[m], bf[n], acc[m][n]);
    }
    float bv[4];
#pragma unroll
    for (int n = 0; n < 4; ++n) bv[n] = bias[cb + wc + n * 16 + lc];
#pragma unroll
    for (int m = 0; m < 4; ++m) {
#pragma unroll
        for (int r = 0; r < 4; ++r) {
            size_t g = rb + wr + m * 16 + lr * 4 + r;       // global row b*512+s
            size_t srow = ((g & 511) << 6) | (g >> 9);      // s*64 + b
#pragma unroll
            for (int n = 0; n < 4; ++n) {
                float v = acc[m][n][r] + bv[n];
                size_t idx = srow * G4 + cb + wc + n * 16 + lc;
                if (XW32) ((float*)xw)[idx] = v;
                else      ((u16*)xw)[idx] = f2bf(v);
            }
        }
    }
}

// ---------------- phase 2: persistent recurrent kernel (R4 core, hardened) -----------
// WGs 0..63: recurrence. WGs 64..255: clock-keeper burners (dependent-FMA chain,
// poll fin flag via sc0sc1 every ~14us). R6-R8 proved 256x128KB WGs co-schedule,
// so this time the burn actually runs -> clean DVFS discriminator.
template <bool XW32>
__global__ __launch_bounds__(256, 1) void k_lstm9(const u16* __restrict__ Ut,
                                                  const void* __restrict__ xw,
                                                  u16* hb, u32* cnt,
                                                  float* __restrict__ out) {
    __shared__ u16 Us[8192 * 8];   // chunk ch=((kk*4+g)*4+lr)*16+lc -> 8 bf16
    const int j = blockIdx.x;
    const int tid = threadIdx.x;

    if (j >= NWG_REC) {
        // ---- clock-keeper burner ----
        const u32* dptr = cnt + 512;   // fin flag, own line
        float burn = 1.0f;
        while (true) {
            u32 d;
            POLLC(d, dptr);
            if (d) break;
#pragma unroll 16
            for (int i = 0; i < 4096; ++i)
                asm volatile("v_fmac_f32 %0, %1, %2" : "+v"(burn) : "v"(1.0000001f), "v"(burn));
        }
        asm volatile("" :: "v"(burn));
        return;
    }

    const int w = tid >> 6, l = tid & 63;
    const int lr = l >> 4, lc = l & 15;
    const int rowbase = w * 16;
    const int col = j * 16 + lc;

    // ---- stage U slice into LDS (one-time) ----
    for (int i = 0; i < 32; ++i) {
        int ch = tid + (i << 8);
        int lc2 = ch & 15, lr2 = (ch >> 4) & 3, g2 = (ch >> 6) & 3, kk2 = ch >> 8;
        const u16* src = Ut + (size_t)(g2 * HH + j * 16 + lc2) * II + kk2 * 32 + lr2 * 8;
        *(s16x8*)(Us + (size_t)ch * 8) = *(const s16x8*)src;
    }

    float cc[4] = {0.f, 0.f, 0.f, 0.f};
    const size_t xwlane = (size_t)(rowbase + lr * 4) * G4 + col;

    const char* xwp[16];   // prefetch pointers -> timestep 1
#pragma unroll
    for (int g = 0; g < 4; ++g)
#pragma unroll
        for (int r = 0; r < 4; ++r) {
            size_t e = (size_t)BB * G4 + xwlane + (size_t)r * G4 + (size_t)g * HH;
            xwp[g * 4 + r] = (const char*)xw + (XW32 ? e * 4 : e * 2);
        }

    float cur[16];   // xw(t=0), plain loads (xw precomputed by prior kernel)
#pragma unroll
    for (int g = 0; g < 4; ++g)
#pragma unroll
        for (int r = 0; r < 4; ++r) {
            size_t e = xwlane + (size_t)r * G4 + (size_t)g * HH;
            cur[g * 4 + r] = XW32 ? ((const float*)xw)[e] : bf2f(((const u16*)xw)[e]);
        }
    u32* mycnt = cnt + (j & 7) * 32;   // arrive counter (128B apart)
    __syncthreads();   // Us ready

    for (int t = 0; t < SS; ++t) {
        f32x4 acc[4][4];
#pragma unroll
        for (int g = 0; g < 4; ++g) {
#pragma unroll
            for (int r = 0; r < 4; ++r) acc[g][0][r] = cur[g * 4 + r];
            acc[g][1] = f32x4{0.f, 0.f, 0.f, 0.f};
            acc[g][2] = f32x4{0.f, 0.f, 0.f, 0.f};
            acc[g][3] = f32x4{0.f, 0.f, 0.f, 0.f};
        }

        // ---- exact-count pipeline: drain, 32 h-loads, 16 xw prefetch, counted waits --
        asm volatile("s_waitcnt vmcnt(0)" ::: "memory");   // makes counts exact
        SBAR();
        const u16* hrow = hb + (size_t)(t & 1) * (BB * HH) +
                          (size_t)(rowbase + lc) * HH + lr * 8;
        s16x8 av[32];
#pragma unroll
        for (int kk = 0; kk < 32; ++kk) HL(av[kk], hrow, kk * 64);

        u32 nxt[16];
#pragma unroll
        for (int q = 0; q < 16; ++q) {
            if (XW32) { XL32(nxt[q], xwp[q]); }
            else      { XL16(nxt[q], xwp[q]); }
        }

#pragma unroll
        for (int kb = 0; kb < 4; ++kb) {
            WAITAV8(40 - 8 * kb, av + kb * 8);   // (24-8kb) h + 16 xw outstanding
            SBAR();                               // rule-#18 fence: nothing crosses
#pragma unroll
            for (int u = 0; u < 8; ++u) {
                const int kk = kb * 8 + u;
#pragma unroll
                for (int g = 0; g < 4; ++g) {
                    const s16x8 bv = *(const s16x8*)(Us +
                        (size_t)(((kk * 4 + g) * 4 + lr) * 16 + lc) * 8);
                    acc[g][kk & 3] = mfma16(av[kk], bv, acc[g][kk & 3]);
                }
            }
        }

        // ---- activations + cell update ----
        float hval[4];
#pragma unroll
        for (int r = 0; r < 4; ++r) {
            float gi = (acc[0][0][r] + acc[0][1][r]) + (acc[0][2][r] + acc[0][3][r]);
            float gf = (acc[1][0][r] + acc[1][1][r]) + (acc[1][2][r] + acc[1][3][r]);
            float gg = (acc[2][0][r] + acc[2][1][r]) + (acc[2][2][r] + acc[2][3][r]);
            float go = (acc[3][0][r] + acc[3][1][r]) + (acc[3][2][r] + acc[3][3][r]);
            float i_ = fsigm(gi);
            float f_ = fsigm(gf);
            float g_ = ftanh(gg);
            float o_ = fsigm(go);
            cc[r] = f_ * cc[r] + i_ * g_;
            hval[r] = o_ * ftanh(cc[r]);
        }

        if (t < SS - 1) {
            // h stores (proven AGENT atomic path) -> drain -> barrier arrive/poll
            u16* hwr = hb + (size_t)((t + 1) & 1) * (BB * HH);
#pragma unroll
            for (int r = 0; r < 4; ++r) {
                int row = rowbase + lr * 4 + r;
                __hip_atomic_store(hwr + (size_t)row * HH + col, f2bf(hval[r]),
                                   __ATOMIC_RELAXED, __HIP_MEMORY_SCOPE_AGENT);
            }
            DRAIN16(nxt);   // h-stores acked at LLC; xw prefetch landed
            SBAR();
            __syncthreads();
            if (tid == 0) {    // fire-and-forget arrive
                u32 one = 1u;
                asm volatile("global_atomic_add %0, %1, off"
                             :: "v"(mycnt), "v"(one) : "memory");
            }
#pragma unroll
            for (int r = 0; r < 4; ++r) {   // out stores overlap the poll
                int row = rowbase + lr * 4 + r;
                out[(size_t)row * (SS * HH) + (size_t)t * HH + col] = hval[r];
            }
            if (tid == 0) {
                u32 tgt = (u32)(t + 1) * 8u;
                while (true) {
                    u32 c0, c1, c2, c3, c4, c5, c6, c7;
                    asm volatile(
                        "global_load_dword %0, %8, off sc0 sc1\n\t"
                        "global_load_dword %1, %8, off offset:128 sc0 sc1\n\t"
                        "global_load_dword %2, %8, off offset:256 sc0 sc1\n\t"
                        "global_load_dword %3, %8, off offset:384 sc0 sc1\n\t"
                        "global_load_dword %4, %8, off offset:512 sc0 sc1\n\t"
                        "global_load_dword %5, %8, off offset:640 sc0 sc1\n\t"
                        "global_load_dword %6, %8, off offset:768 sc0 sc1\n\t"
                        "global_load_dword %7, %8, off offset:896 sc0 sc1\n\t"
                        "s_waitcnt vmcnt(0)"
                        : "=v"(c0), "=v"(c1), "=v"(c2), "=v"(c3),
                          "=v"(c4), "=v"(c5), "=v"(c6), "=v"(c7)
                        : "v"(cnt));
                    if (c0 >= tgt && c1 >= tgt && c2 >= tgt && c3 >= tgt &&
                        c4 >= tgt && c5 >= tgt && c6 >= tgt && c7 >= tgt) break;
                    __builtin_amdgcn_s_sleep(1);
                }
            }
            __syncthreads();
            if (t < SS - 2) {
#pragma unroll
                for (int q = 0; q < 16; ++q)
                    xwp[q] += (size_t)BB * G4 * (XW32 ? 4 : 2);
            }
#pragma unroll
            for (int q = 0; q < 16; ++q)
                cur[q] = XW32 ? __uint_as_float(nxt[q]) : __uint_as_float(nxt[q] << 16);
        } else {
#pragma unroll
            for (int r = 0; r < 4; ++r) {
                int row = rowbase + lr * 4 + r;
                out[(size_t)row * (SS * HH) + (size_t)t * HH + col] = hval[r];
                out[(size_t)(BB * SS * HH) + (size_t)row * HH + col] = hval[r];
                out[(size_t)(BB * SS * HH + BB * HH) + (size_t)row * HH + col] = cc[r];
            }
            if (j == 0 && tid == 0) {   // release burners
                __hip_atomic_store(cnt + 512, 1u,
                                   __ATOMIC_RELAXED, __HIP_MEMORY_SCOPE_AGENT);
            }
        }
    }
}

// ---------------- host launch ----------------
extern "C" void kernel_launch(void* const* d_in, const int* in_sizes, int n_in,
                              void* d_out, int out_size, void* d_ws, size_t ws_size,
                              hipStream_t stream) {
    const float* x = (const float*)d_in[0];
    const float* W = (const float*)d_in[1];
    const float* U = (const float*)d_in[2];
    const float* b = (const float*)d_in[3];
    float* out = (float*)d_out;

    size_t xb_b  = (size_t)BB * SS * II * 2;   // 64 MiB
    size_t wt_b  = (size_t)G4 * II * 2;        // 8 MiB each
    size_t hb_b  = (size_t)2 * BB * HH * 2;    // 256 KiB
    size_t xw32_b = (size_t)BB * SS * G4 * 4;  // 512 MiB
    size_t xw16_b = xw32_b / 2;
    size_t base = xb_b + 2 * wt_b;

    int mode = (base + xw32_b + hb_b + 4096 <= ws_size) ? 0 : 1;

    char* p = (char*)d_ws;
    u16* xb = (u16*)p;
    u16* Wt = (u16*)(p + xb_b);
    u16* Ut = (u16*)(p + xb_b + wt_b);
    char* q = p + base;
    void* xw = (void*)q;
    q += (mode == 0) ? xw32_b : xw16_b;
    u16* hb = (u16*)q; q += hb_b;
    u32* cnt = (u32*)q;   // 4KB: 8 counters @128B + fin flag @ u32 idx 512

    k_convert_x<<<2048, 256, 0, stream>>>(x, xb, BB * SS * II / 4);
    k_transpose_bf<<<dim3(G4 / 32, II / 32), dim3(32, 32), 0, stream>>>(W, Wt, II, G4);
    k_transpose_bf<<<dim3(G4 / 32, II / 32), dim3(32, 32), 0, stream>>>(U, Ut, II, G4);
    k_zero<<<64, 256, 0, stream>>>((u64*)hb, (u64*)cnt);

    if (mode == 0) {
        k_gemm_xw<true><<<8192, 256, 0, stream>>>(xb, Wt, b, xw);
        k_lstm9<true><<<NWG_TOT, 256, 0, stream>>>(Ut, xw, hb, cnt, out);
    } else {
        k_gemm_xw<false><<<8192, 256, 0, stream>>>(xb, Wt, b, xw);
        k_lstm9<false><<<NWG_TOT, 256, 0, stream>>>(Ut, xw, hb, cnt, out);
    }
}